// Round 4
// baseline (147.614 us; speedup 1.0000x reference)
//
#include <hip/hip_runtime.h>

constexpr int T_TOTAL = 100000;
constexpr int RANK    = 128;
constexpr int W       = 11;
constexpr int PAD     = 5;            // (W-1)/2
constexpr int T_TILE  = 32;
constexpr int ROWS    = T_TILE + W - 1;   // 42
constexpr int BLOCK   = 256;
constexpr int LDSP    = RANK + 4;     // +16B/row: odd quad rotation -> balanced b128 phases

// 16-lane sum+broadcast butterfly on the VALU pipe (DPP).
// 0xB1 quad_perm xor1, 0x4E quad_perm xor2, 0x141 row_half_mirror, 0x140 row_mirror.
template <int CTRL>
__device__ __forceinline__ float dpp_radd(float v) {
    int o = __builtin_amdgcn_update_dpp(0, __float_as_int(v), CTRL, 0xF, 0xF, true);
    return v + __int_as_float(o);
}

__device__ __forceinline__ float group_reduce16(float s) {
    s = dpp_radd<0xB1>(s);
    s = dpp_radd<0x4E>(s);
    s = dpp_radd<0x141>(s);
    s = dpp_radd<0x140>(s);
    return s;
}

__global__ __launch_bounds__(BLOCK, 7) void attn_win_kernel(const float* __restrict__ in,
                                                            float* __restrict__ out) {
    __shared__ float lds[ROWS][LDSP];
    const int t0  = blockIdx.x * T_TILE;
    const int tid = threadIdx.x;

    // ---- Stage rows [t0-PAD, t0+T_TILE+PAD) into LDS, zero-fill out-of-range ----
    const int n4 = ROWS * (RANK / 4);   // 42*32 = 1344 float4 chunks
    for (int idx = tid; idx < n4; idx += BLOCK) {
        const int row  = idx >> 5;
        const int c4   = idx & 31;
        const int grow = t0 - PAD + row;
        float4 v = make_float4(0.f, 0.f, 0.f, 0.f);
        if ((unsigned)grow < (unsigned)T_TOTAL)
            v = *reinterpret_cast<const float4*>(in + (size_t)grow * RANK + c4 * 4);
        *reinterpret_cast<float4*>(&lds[row][c4 * 4]) = v;
    }
    __syncthreads();

    // ---- Compute: 16-lane group owns one t; lane owns 8 r's ----
    const int wave = tid >> 6;
    const int lane = tid & 63;
    const int g    = lane >> 4;
    const int sub  = lane & 15;
    const int rbase = sub * 8;
    constexpr float LOG2E = 1.4426950408889634f;

    #pragma unroll
    for (int it = 0; it < T_TILE / 16; ++it) {
        const int t_local = wave * 8 + it * 4 + g;   // 4 waves x 2 its x 4 groups = 32 t's
        const int t       = t0 + t_local;            // grid exact: always < T_TOTAL

        const float4 x0 = *reinterpret_cast<const float4*>(&lds[t_local + PAD][rbase]);
        const float4 x1 = *reinterpret_cast<const float4*>(&lds[t_local + PAD][rbase + 4]);

        // pre-scale by log2e: dots come out in exp2 domain
        const float xs[8] = { x0.x * LOG2E, x0.y * LOG2E, x0.z * LOG2E, x0.w * LOG2E,
                              x1.x * LOG2E, x1.y * LOG2E, x1.z * LOG2E, x1.w * LOG2E };

        // self score s5 = |x|^2 * log2e ; it is the max (cross-score gap is >6 sigma)
        float s5 = xs[0] * x0.x + xs[1] * x0.y + xs[2] * x0.z + xs[3] * x0.w
                 + xs[4] * x1.x + xs[5] * x1.y + xs[6] * x1.z + xs[7] * x1.w;
        s5 = group_reduce16(s5);

        // j = PAD contributes weight exp2(0)=1, row = x
        float sum = 1.0f;
        float acc[8] = { x0.x, x0.y, x0.z, x0.w, x1.x, x1.y, x1.z, x1.w };

        #pragma unroll
        for (int j = 0; j < W; ++j) {
            if (j == PAD) continue;
            const float4 b0 = *reinterpret_cast<const float4*>(&lds[t_local + j][rbase]);
            const float4 b1 = *reinterpret_cast<const float4*>(&lds[t_local + j][rbase + 4]);
            float s = b0.x * xs[0] + b0.y * xs[1] + b0.z * xs[2] + b0.w * xs[3]
                    + b1.x * xs[4] + b1.y * xs[5] + b1.z * xs[6] + b1.w * xs[7];
            s = group_reduce16(s);
            const float w = exp2f(s - s5);   // out-of-range rows: s=0 -> matches ref zero-pad
            sum += w;
            acc[0] = fmaf(w, b0.x, acc[0]);
            acc[1] = fmaf(w, b0.y, acc[1]);
            acc[2] = fmaf(w, b0.z, acc[2]);
            acc[3] = fmaf(w, b0.w, acc[3]);
            acc[4] = fmaf(w, b1.x, acc[4]);
            acc[5] = fmaf(w, b1.y, acc[5]);
            acc[6] = fmaf(w, b1.z, acc[6]);
            acc[7] = fmaf(w, b1.w, acc[7]);
        }

        const float inv = 1.f / sum;
        float* op = out + (size_t)t * RANK + rbase;
        *reinterpret_cast<float4*>(op) =
            make_float4(acc[0] * inv, acc[1] * inv, acc[2] * inv, acc[3] * inv);
        *reinterpret_cast<float4*>(op + 4) =
            make_float4(acc[4] * inv, acc[5] * inv, acc[6] * inv, acc[7] * inv);
    }
}

extern "C" void kernel_launch(void* const* d_in, const int* in_sizes, int n_in,
                              void* d_out, int out_size, void* d_ws, size_t ws_size,
                              hipStream_t stream) {
    const float* in  = (const float*)d_in[0];
    float*       out = (float*)d_out;
    const int grid = T_TOTAL / T_TILE;   // 3125, exact
    attn_win_kernel<<<grid, BLOCK, 0, stream>>>(in, out);
}

// Round 5
// 139.329 us; speedup vs baseline: 1.0595x; 1.0595x over previous
//
#include <hip/hip_runtime.h>

constexpr int T_TOTAL = 100000;
constexpr int RANK    = 128;
constexpr int W       = 11;
constexpr int PAD     = 5;            // (W-1)/2
constexpr int T_TILE  = 32;
constexpr int ROWS    = T_TILE + W - 1;   // 42
constexpr int BLOCK   = 256;
constexpr int LDSP    = RANK + 4;     // +16B/row: bank rotation by 4 per row

// 16-lane sum+broadcast butterfly on the VALU pipe (DPP).
// 0xB1 quad_perm xor1, 0x4E quad_perm xor2, 0x141 row_half_mirror, 0x140 row_mirror.
template <int CTRL>
__device__ __forceinline__ float dpp_radd(float v) {
    int o = __builtin_amdgcn_update_dpp(0, __float_as_int(v), CTRL, 0xF, 0xF, true);
    return v + __int_as_float(o);
}

__device__ __forceinline__ float group_reduce16(float s) {
    s = dpp_radd<0xB1>(s);
    s = dpp_radd<0x4E>(s);
    s = dpp_radd<0x141>(s);
    s = dpp_radd<0x140>(s);
    return s;
}

__global__ __launch_bounds__(BLOCK, 6) void attn_win_kernel(const float* __restrict__ in,
                                                            float* __restrict__ out) {
    __shared__ float lds[ROWS][LDSP];
    const int t0  = blockIdx.x * T_TILE;
    const int tid = threadIdx.x;

    // ---- Stage rows [t0-PAD, t0+T_TILE+PAD) into LDS, zero-fill out-of-range ----
    const int n4 = ROWS * (RANK / 4);   // 42*32 = 1344 float4 chunks
    for (int idx = tid; idx < n4; idx += BLOCK) {
        const int row  = idx >> 5;
        const int c4   = idx & 31;
        const int grow = t0 - PAD + row;
        float4 v = make_float4(0.f, 0.f, 0.f, 0.f);
        if ((unsigned)grow < (unsigned)T_TOTAL)
            v = *reinterpret_cast<const float4*>(in + (size_t)grow * RANK + c4 * 4);
        *reinterpret_cast<float4*>(&lds[row][c4 * 4]) = v;
    }
    __syncthreads();

    // ---- Compute: 16-lane group owns one t; lane owns 8 r's ----
    const int wave = tid >> 6;
    const int lane = tid & 63;
    const int g    = lane >> 4;
    const int sub  = lane & 15;
    const int rbase = sub * 8;
    constexpr float LOG2E = 1.4426950408889634f;

    #pragma unroll
    for (int it = 0; it < T_TILE / 16; ++it) {
        const int t_local = wave * 8 + it * 4 + g;   // 4 waves x 2 its x 4 groups = 32 t's
        const int t       = t0 + t_local;            // grid exact: always < T_TOTAL

        const float4 x0 = *reinterpret_cast<const float4*>(&lds[t_local + PAD][rbase]);
        const float4 x1 = *reinterpret_cast<const float4*>(&lds[t_local + PAD][rbase + 4]);

        // pre-scale x by log2e: dots come out in exp2 domain (scalarized, rule #20)
        const float xs0 = x0.x * LOG2E, xs1 = x0.y * LOG2E, xs2 = x0.z * LOG2E, xs3 = x0.w * LOG2E;
        const float xs4 = x1.x * LOG2E, xs5 = x1.y * LOG2E, xs6 = x1.z * LOG2E, xs7 = x1.w * LOG2E;

        // self score s5 = |x|^2 * log2e ; it is the softmax max (cross-gap > 6 sigma)
        float s5 = xs0 * x0.x + xs1 * x0.y + xs2 * x0.z + xs3 * x0.w
                 + xs4 * x1.x + xs5 * x1.y + xs6 * x1.z + xs7 * x1.w;
        s5 = group_reduce16(s5);

        // j = PAD contributes weight exp2(0)=1, row = x
        float sum = 1.0f;
        float a0 = x0.x, a1 = x0.y, a2 = x0.z, a3 = x0.w;
        float a4 = x1.x, a5 = x1.y, a6 = x1.z, a7 = x1.w;

        #pragma unroll
        for (int j = 0; j < W; ++j) {
            if (j == PAD) continue;
            const float4 b0 = *reinterpret_cast<const float4*>(&lds[t_local + j][rbase]);
            const float4 b1 = *reinterpret_cast<const float4*>(&lds[t_local + j][rbase + 4]);
            float s = b0.x * xs0 + b0.y * xs1 + b0.z * xs2 + b0.w * xs3
                    + b1.x * xs4 + b1.y * xs5 + b1.z * xs6 + b1.w * xs7;
            s = group_reduce16(s);
            const float w = exp2f(s - s5);   // OOB rows: s=0 -> matches ref zero-pad path
            sum += w;
            a0 = fmaf(w, b0.x, a0);
            a1 = fmaf(w, b0.y, a1);
            a2 = fmaf(w, b0.z, a2);
            a3 = fmaf(w, b0.w, a3);
            a4 = fmaf(w, b1.x, a4);
            a5 = fmaf(w, b1.y, a5);
            a6 = fmaf(w, b1.z, a6);
            a7 = fmaf(w, b1.w, a7);
        }

        const float inv = 1.f / sum;
        float* op = out + (size_t)t * RANK + rbase;
        *reinterpret_cast<float4*>(op)     = make_float4(a0 * inv, a1 * inv, a2 * inv, a3 * inv);
        *reinterpret_cast<float4*>(op + 4) = make_float4(a4 * inv, a5 * inv, a6 * inv, a7 * inv);
    }
}

extern "C" void kernel_launch(void* const* d_in, const int* in_sizes, int n_in,
                              void* d_out, int out_size, void* d_ws, size_t ws_size,
                              hipStream_t stream) {
    const float* in  = (const float*)d_in[0];
    float*       out = (float*)d_out;
    const int grid = T_TOTAL / T_TILE;   // 3125, exact
    attn_win_kernel<<<grid, BLOCK, 0, stream>>>(in, out);
}

// Round 6
// 32.379 us; speedup vs baseline: 4.5589x; 4.3030x over previous
//
#include <hip/hip_runtime.h>

constexpr int T_TOTAL = 100000;
constexpr int RANK    = 128;
constexpr int W       = 11;
constexpr int PAD     = 5;            // (W-1)/2
constexpr int T_TILE  = 32;
constexpr int ROWS    = T_TILE + W - 1;   // 42
constexpr int BLOCK   = 256;
constexpr int LDSP    = RANK + 4;     // +16B/row: bank rotation by 4 per row

// 16-lane sum+broadcast butterfly on the VALU pipe (DPP).
// 0xB1 quad_perm xor1, 0x4E quad_perm xor2, 0x141 row_half_mirror, 0x140 row_mirror.
template <int CTRL>
__device__ __forceinline__ float dpp_radd(float v) {
    int o = __builtin_amdgcn_update_dpp(0, __float_as_int(v), CTRL, 0xF, 0xF, true);
    return v + __int_as_float(o);
}

__device__ __forceinline__ float group_reduce16(float s) {
    s = dpp_radd<0xB1>(s);
    s = dpp_radd<0x4E>(s);
    s = dpp_radd<0x141>(s);
    s = dpp_radd<0x140>(s);
    return s;
}

// NOTE: no min-waves arg — (256,6)/(256,7) capped VGPRs (40/36) and spilled
// wholesale to scratch (WRITE_SIZE 50->366 MB, dur 139-147us). LDS=22.5KB already
// permits 7 blocks/CU; just don't constrain the allocator.
__global__ __launch_bounds__(BLOCK) void attn_win_kernel(const float* __restrict__ in,
                                                         float* __restrict__ out) {
    __shared__ float lds[ROWS][LDSP];
    const int t0  = blockIdx.x * T_TILE;
    const int tid = threadIdx.x;

    // ---- Stage rows [t0-PAD, t0+T_TILE+PAD) into LDS, zero-fill out-of-range ----
    const int n4 = ROWS * (RANK / 4);   // 42*32 = 1344 float4 chunks
    for (int idx = tid; idx < n4; idx += BLOCK) {
        const int row  = idx >> 5;
        const int c4   = idx & 31;
        const int grow = t0 - PAD + row;
        float4 v = make_float4(0.f, 0.f, 0.f, 0.f);
        if ((unsigned)grow < (unsigned)T_TOTAL)
            v = *reinterpret_cast<const float4*>(in + (size_t)grow * RANK + c4 * 4);
        *reinterpret_cast<float4*>(&lds[row][c4 * 4]) = v;
    }
    __syncthreads();

    // ---- Compute: 16-lane group owns one t; lane owns 8 r's ----
    const int wave = tid >> 6;
    const int lane = tid & 63;
    const int g    = lane >> 4;
    const int sub  = lane & 15;
    const int rbase = sub * 8;
    constexpr float LOG2E = 1.4426950408889634f;

    #pragma unroll 1   // keep one t-computation live at a time -> ~55 regs, no spill
    for (int it = 0; it < T_TILE / 16; ++it) {
        const int t_local = wave * 8 + it * 4 + g;   // 4 waves x 2 its x 4 groups = 32 t's
        const int t       = t0 + t_local;            // grid exact: always < T_TOTAL

        const float4 x0 = *reinterpret_cast<const float4*>(&lds[t_local + PAD][rbase]);
        const float4 x1 = *reinterpret_cast<const float4*>(&lds[t_local + PAD][rbase + 4]);

        // pre-scale x by log2e: dots come out in exp2 domain
        const float xs0 = x0.x * LOG2E, xs1 = x0.y * LOG2E, xs2 = x0.z * LOG2E, xs3 = x0.w * LOG2E;
        const float xs4 = x1.x * LOG2E, xs5 = x1.y * LOG2E, xs6 = x1.z * LOG2E, xs7 = x1.w * LOG2E;

        // self score s5 = |x|^2 * log2e ; it is the softmax max (cross-gap > 6 sigma)
        float s5 = xs0 * x0.x + xs1 * x0.y + xs2 * x0.z + xs3 * x0.w
                 + xs4 * x1.x + xs5 * x1.y + xs6 * x1.z + xs7 * x1.w;
        s5 = group_reduce16(s5);

        // j = PAD contributes weight exp2(0)=1, row = x
        float sum = 1.0f;
        float a0 = x0.x, a1 = x0.y, a2 = x0.z, a3 = x0.w;
        float a4 = x1.x, a5 = x1.y, a6 = x1.z, a7 = x1.w;

        #pragma unroll
        for (int j = 0; j < W; ++j) {
            if (j == PAD) continue;
            const float4 b0 = *reinterpret_cast<const float4*>(&lds[t_local + j][rbase]);
            const float4 b1 = *reinterpret_cast<const float4*>(&lds[t_local + j][rbase + 4]);
            float s = b0.x * xs0 + b0.y * xs1 + b0.z * xs2 + b0.w * xs3
                    + b1.x * xs4 + b1.y * xs5 + b1.z * xs6 + b1.w * xs7;
            s = group_reduce16(s);
            const float w = exp2f(s - s5);   // OOB rows: s=0 -> matches ref zero-pad path
            sum += w;
            a0 = fmaf(w, b0.x, a0);
            a1 = fmaf(w, b0.y, a1);
            a2 = fmaf(w, b0.z, a2);
            a3 = fmaf(w, b0.w, a3);
            a4 = fmaf(w, b1.x, a4);
            a5 = fmaf(w, b1.y, a5);
            a6 = fmaf(w, b1.z, a6);
            a7 = fmaf(w, b1.w, a7);
        }

        const float inv = 1.f / sum;
        float* op = out + (size_t)t * RANK + rbase;
        *reinterpret_cast<float4*>(op)     = make_float4(a0 * inv, a1 * inv, a2 * inv, a3 * inv);
        *reinterpret_cast<float4*>(op + 4) = make_float4(a4 * inv, a5 * inv, a6 * inv, a7 * inv);
    }
}

extern "C" void kernel_launch(void* const* d_in, const int* in_sizes, int n_in,
                              void* d_out, int out_size, void* d_ws, size_t ws_size,
                              hipStream_t stream) {
    const float* in  = (const float*)d_in[0];
    float*       out = (float*)d_out;
    const int grid = T_TOTAL / T_TILE;   // 3125, exact
    attn_win_kernel<<<grid, BLOCK, 0, stream>>>(in, out);
}